// Round 3
// baseline (257.400 us; speedup 1.0000x reference)
//
#include <hip/hip_runtime.h>
#include <hip/hip_bf16.h>

// PHOG: lap = dw3x3(x, laplacian); gx,gy = dw3x3(lap, sobel); mag/ang -> 9-bin
// hist over pyramid cells (1+4+16), L1-ish then L2 normalize.
//
// R3 structure: NO LDS staging. Each thread computes a 4-wide x 8-tall output
// tile straight from global memory (12 rows x 4 float2 loads); the 3x window
// overlap between neighboring threads is served by L1 (block working set
// ~20KB < 32KB L1). Removes: stage->barrier serialization, all LDS latency
// and bank conflicts, and the LDS occupancy cap. Block = 256 threads covers
// 64w x 128h = 2 level-2 cells (waves 0,1 -> top cell, 2,3 -> bottom).
// Cumulative-histogram binning identical to R2 (verified, absmax 2e-3).

#define H_IMG 256
#define W_IMG 256

// x rows u (above), m (center), d (below) -> 6 lap values; edge masks zero
// lap outside the image (reference zero-pads lap, not lap-of-padded-x).
__device__ __forceinline__ void lap_row6(float dst[6], const float u[8], const float m[8],
                                         const float d[8], float wm0, float wm5, float rowm) {
#pragma unroll
  for (int c = 0; c < 6; ++c) {
    float v = (u[c + 1] + d[c + 1]) + fmaf(-4.f, m[c + 1], m[c] + m[c + 2]);
    dst[c] = v * rowm;
  }
  dst[0] *= wm0;
  dst[5] *= wm5;
}

// gradient + cumulative-binning for one output row (4 px) from lap rows A,B,C
// acc[0..8] = sums of mag where ang >= b_i (monotone boundaries), acc[9] = total
__device__ __forceinline__ void out_row4(const float A[6], const float B[6], const float C[6],
                                         float acc[10]) {
  float cs[6], dd[6];
#pragma unroll
  for (int c = 0; c < 6; ++c) {
    cs[c] = A[c] + fmaf(2.f, B[c], C[c]);
    dd[c] = C[c] - A[c];
  }
#pragma unroll
  for (int c = 0; c < 4; ++c) {
    float gx = cs[c + 2] - cs[c];
    float gy = fmaf(2.f, dd[c + 1], dd[c] + dd[c + 2]);
    float mag = __builtin_amdgcn_sqrtf(fmaf(gx, gx, fmaf(gy, gy, 1e-8f)));
    bool neg = gy < 0.f;
    float fx = neg ? -gx : gx;
    float fy = neg ? -gy : gy;
    float u, v;
    u = 0.17364817766693033f * fx; v = 0.984807753012208f * fy;
    acc[0] += (u <= v) ? mag : 0.f;
    acc[8] += (u <= -v) ? mag : 0.f;
    u = 0.5f * fx; v = 0.8660254037844387f * fy;
    acc[1] += (u <= v) ? mag : 0.f;
    acc[7] += (u <= -v) ? mag : 0.f;
    u = 0.766044443118978f * fx; v = 0.6427876096865393f * fy;
    acc[2] += (u <= v) ? mag : 0.f;
    acc[6] += (u <= -v) ? mag : 0.f;
    u = 0.9396926207859084f * fx; v = 0.3420201433256687f * fy;
    acc[3] += (u <= v) ? mag : 0.f;
    acc[5] += (u <= -v) ? mag : 0.f;
    acc[4] += (fx <= 0.f) ? mag : 0.f;
    acc[9] += mag;
  }
}

// one x row (8 floats, window cols gc0-2..gc0+5) from global, zero-filled OOB
__device__ __forceinline__ void load_grow(const float* __restrict__ xim, int gr, bool valid,
                                          int o0, int o1, int o2, int o3,
                                          float mlo, float mhi, float r[8]) {
  if (valid) {
    const float* p = xim + gr * W_IMG;
    float2 a = *reinterpret_cast<const float2*>(p + o0);
    float2 b = *reinterpret_cast<const float2*>(p + o1);
    float2 c = *reinterpret_cast<const float2*>(p + o2);
    float2 d = *reinterpret_cast<const float2*>(p + o3);
    r[0] = a.x * mlo; r[1] = a.y * mlo;
    r[2] = b.x;       r[3] = b.y;
    r[4] = c.x;       r[5] = c.y;
    r[6] = d.x * mhi; r[7] = d.y * mhi;
  } else {
#pragma unroll
    for (int i = 0; i < 8; ++i) r[i] = 0.f;
  }
}

__global__ __launch_bounds__(256, 5) void phog_hist_kernel(const float* __restrict__ x,
                                                           float* __restrict__ hist2) {
  const int tile = blockIdx.x;  // 0..7: (tr2=tile>>2 in 0..1, tc=tile&3 in 0..3)
  const int bc = blockIdx.y;    // 0..511
  const int tr2 = tile >> 2;
  const int tc = tile & 3;
  const int R0 = tr2 * 128;     // block covers rows R0..R0+127 (2 cells)
  const int C0 = tc * 64;
  const int tid = threadIdx.x;
  const int tcol = tid & 15;    // 0..15 -> 4 cols each
  const int trow = tid >> 4;    // 0..15 -> 8 rows each

  const float* xim = x + (size_t)bc * (H_IMG * W_IMG);

  const int gr0 = R0 + 8 * trow;  // first output row
  const int gc0 = C0 + 4 * tcol;  // first output col
  const int bcol = gc0 - 2;       // window col 0 (global)

  // clamped float2 offsets + masks for the 2 edge float2s
  const int o0 = (bcol < 0) ? 0 : bcol;
  const int o1 = gc0;
  const int o2 = gc0 + 2;
  const int o3 = (gc0 + 4 > 254) ? 254 : (gc0 + 4);
  const float mlo = (bcol >= 0) ? 1.f : 0.f;          // cols gc0-2,gc0-1
  const float mhi = (gc0 + 5 <= 255) ? 1.f : 0.f;     // cols gc0+4,gc0+5

  const bool vlo = gr0 > 0;     // x rows gr0-2, gr0-1 valid?
  const bool vhi = gr0 < 248;   // x rows gr0+8, gr0+9 valid?
  const float rm_first = vlo ? 1.f : 0.f;  // lap row gr0-1
  const float rm_last = vhi ? 1.f : 0.f;   // lap row gr0+8
  const float wm0 = (gc0 >= 1) ? 1.f : 0.f;     // lap col gc0-1
  const float wm5 = (gc0 + 4 <= 255) ? 1.f : 0.f;  // lap col gc0+4

  float acc[10];
#pragma unroll
  for (int k = 0; k < 10; ++k) acc[k] = 0.f;

  float xr0[8], xr1[8], xr2[8], lA[6], lB[6], lC[6];

  // x window rows: i=0..11 at global row gr0-2+i
  load_grow(xim, gr0 - 2, vlo, o0, o1, o2, o3, mlo, mhi, xr0);
  load_grow(xim, gr0 - 1, vlo, o0, o1, o2, o3, mlo, mhi, xr1);
  load_grow(xim, gr0 + 0, true, o0, o1, o2, o3, mlo, mhi, xr2);
  lap_row6(lA, xr0, xr1, xr2, wm0, wm5, rm_first);   // lap 0
  load_grow(xim, gr0 + 1, true, o0, o1, o2, o3, mlo, mhi, xr0);
  lap_row6(lB, xr1, xr2, xr0, wm0, wm5, 1.f);        // lap 1
  load_grow(xim, gr0 + 2, true, o0, o1, o2, o3, mlo, mhi, xr1);
  lap_row6(lC, xr2, xr0, xr1, wm0, wm5, 1.f);        // lap 2
  out_row4(lA, lB, lC, acc);                         // out 0
  load_grow(xim, gr0 + 3, true, o0, o1, o2, o3, mlo, mhi, xr2);
  lap_row6(lA, xr0, xr1, xr2, wm0, wm5, 1.f);        // lap 3
  out_row4(lB, lC, lA, acc);                         // out 1
  load_grow(xim, gr0 + 4, true, o0, o1, o2, o3, mlo, mhi, xr0);
  lap_row6(lB, xr1, xr2, xr0, wm0, wm5, 1.f);        // lap 4
  out_row4(lC, lA, lB, acc);                         // out 2
  load_grow(xim, gr0 + 5, true, o0, o1, o2, o3, mlo, mhi, xr1);
  lap_row6(lC, xr2, xr0, xr1, wm0, wm5, 1.f);        // lap 5
  out_row4(lA, lB, lC, acc);                         // out 3
  load_grow(xim, gr0 + 6, true, o0, o1, o2, o3, mlo, mhi, xr2);
  lap_row6(lA, xr0, xr1, xr2, wm0, wm5, 1.f);        // lap 6
  out_row4(lB, lC, lA, acc);                         // out 4
  load_grow(xim, gr0 + 7, true, o0, o1, o2, o3, mlo, mhi, xr0);
  lap_row6(lB, xr1, xr2, xr0, wm0, wm5, 1.f);        // lap 7
  out_row4(lC, lA, lB, acc);                         // out 5
  load_grow(xim, gr0 + 8, vhi, o0, o1, o2, o3, mlo, mhi, xr1);
  lap_row6(lC, xr2, xr0, xr1, wm0, wm5, 1.f);        // lap 8
  out_row4(lA, lB, lC, acc);                         // out 6
  load_grow(xim, gr0 + 9, vhi, o0, o1, o2, o3, mlo, mhi, xr2);
  lap_row6(lA, xr0, xr1, xr2, wm0, wm5, rm_last);    // lap 9
  out_row4(lB, lC, lA, acc);                         // out 7

  // wave reduce (64 lanes; each wave lies entirely within one cell)
#pragma unroll
  for (int k = 0; k < 10; ++k) {
    float v = acc[k];
#pragma unroll
    for (int off = 32; off > 0; off >>= 1) v += __shfl_xor(v, off);
    acc[k] = v;
  }

  __shared__ float hred[4][10];
  __shared__ float hs[2][10];
  int lane = tid & 63;
  int wave = tid >> 6;
  if (lane == 0) {
#pragma unroll
    for (int k = 0; k < 10; ++k) hred[wave][k] = acc[k];
  }
  __syncthreads();
  if (tid < 10) hs[0][tid] = hred[0][tid] + hred[1][tid];
  if (tid >= 32 && tid < 42) hs[1][tid - 32] = hred[2][tid - 32] + hred[3][tid - 32];
  __syncthreads();

  const int cell_top = (2 * tr2) * 4 + tc;
  const int cell_bot = (2 * tr2 + 1) * 4 + tc;
  if (tid < 9) {
    float h = (tid == 0) ? ((hs[0][9] - hs[0][0]) + hs[0][8]) : (hs[0][tid - 1] - hs[0][tid]);
    hist2[(bc * 16 + cell_top) * 9 + tid] = h;
  }
  if (tid >= 32 && tid < 41) {
    int k = tid - 32;
    float h = (k == 0) ? ((hs[1][9] - hs[1][0]) + hs[1][8]) : (hs[1][k - 1] - hs[1][k]);
    hist2[(bc * 16 + cell_bot) * 9 + k] = h;
  }
}

__global__ __launch_bounds__(256) void phog_norm_kernel(const float* __restrict__ hist2,
                                                        float* __restrict__ out) {
  int t = blockIdx.x * 256 + threadIdx.x;
  if (t >= 32 * 336) return;
  int b = t / 336;
  int r = t - b * 336;

  float h[9];
  if (r < 16) {
    const float* p = hist2 + (b * 16 + r) * 144;
#pragma unroll
    for (int k = 0; k < 9; ++k) {
      float s = 0.f;
#pragma unroll
      for (int cell = 0; cell < 16; ++cell) s += p[cell * 9 + k];
      h[k] = s;
    }
  } else if (r < 80) {
    int q = r - 16;
    int c = q >> 2;
    int cell = q & 3;
    int r1 = cell >> 1, c1 = cell & 1;
    const float* p = hist2 + (b * 16 + c) * 144;
    int i00 = ((2 * r1) * 4 + 2 * c1) * 9;
    int i01 = ((2 * r1) * 4 + 2 * c1 + 1) * 9;
    int i10 = ((2 * r1 + 1) * 4 + 2 * c1) * 9;
    int i11 = ((2 * r1 + 1) * 4 + 2 * c1 + 1) * 9;
#pragma unroll
    for (int k = 0; k < 9; ++k) h[k] = (p[i00 + k] + p[i01 + k]) + (p[i10 + k] + p[i11 + k]);
  } else {
    int q = r - 80;
    int c = q >> 4;
    int cell = q & 15;
    const float* p = hist2 + ((b * 16 + c) * 16 + cell) * 9;
#pragma unroll
    for (int k = 0; k < 9; ++k) h[k] = p[k];
  }

  float s = 0.f;
#pragma unroll
  for (int k = 0; k < 9; ++k) s += h[k];
  float inv = 1.f / (s + 1e-8f);
#pragma unroll
  for (int k = 0; k < 9; ++k) h[k] *= inv;
  float n2 = 0.f;
#pragma unroll
  for (int k = 0; k < 9; ++k) n2 = fmaf(h[k], h[k], n2);
  float nrm = sqrtf(n2);
  float inv2 = 1.f / fmaxf(nrm, 1e-12f);
#pragma unroll
  for (int k = 0; k < 9; ++k) out[t * 9 + k] = h[k] * inv2;
}

extern "C" void kernel_launch(void* const* d_in, const int* in_sizes, int n_in,
                              void* d_out, int out_size, void* d_ws, size_t ws_size,
                              hipStream_t stream) {
  const float* x = (const float*)d_in[0];
  float* out = (float*)d_out;
  float* hist2 = (float*)d_ws;  // 512*16*9 floats = 294912 B

  dim3 g1(8, 512);
  phog_hist_kernel<<<g1, 256, 0, stream>>>(x, hist2);

  int total = 32 * 336;
  phog_norm_kernel<<<(total + 255) / 256, 256, 0, stream>>>(hist2, out);
}

// Round 4
// 103.549 us; speedup vs baseline: 2.4858x; 2.4858x over previous
//
#include <hip/hip_runtime.h>
#include <hip/hip_bf16.h>

// PHOG: lap = dw3x3(x, laplacian); gx,gy = dw3x3(lap, sobel); mag/ang -> 9-bin
// hist over pyramid cells (1+4+16), L1-ish then L2 normalize.
//
// R4 = R3 structure (no LDS staging; 4w x 8t per-thread tiles straight from
// global; L1/L2 serve the 3x window overlap) with the register budget FIXED:
// R3's __launch_bounds__(256,5) capped VGPRs at 48 -> full spill of the
// ~100-float live set (WRITE_SIZE 579 MB of scratch). (256,4) caps at 128,
// which fits the live set. Binning math unchanged (verified absmax 2e-3).

#define H_IMG 256
#define W_IMG 256

__device__ __forceinline__ void lap_row6(float dst[6], const float u[8], const float m[8],
                                         const float d[8], float wm0, float wm5, float rowm) {
#pragma unroll
  for (int c = 0; c < 6; ++c) {
    float v = (u[c + 1] + d[c + 1]) + fmaf(-4.f, m[c + 1], m[c] + m[c + 2]);
    dst[c] = v * rowm;
  }
  dst[0] *= wm0;
  dst[5] *= wm5;
}

// gradient + cumulative-binning for one output row (4 px) from lap rows A,B,C
// acc[0..8] = sums of mag where ang >= b_i (monotone boundaries), acc[9] = total
__device__ __forceinline__ void out_row4(const float A[6], const float B[6], const float C[6],
                                         float acc[10]) {
  float cs[6], dd[6];
#pragma unroll
  for (int c = 0; c < 6; ++c) {
    cs[c] = A[c] + fmaf(2.f, B[c], C[c]);
    dd[c] = C[c] - A[c];
  }
#pragma unroll
  for (int c = 0; c < 4; ++c) {
    float gx = cs[c + 2] - cs[c];
    float gy = fmaf(2.f, dd[c + 1], dd[c] + dd[c + 2]);
    float mag = __builtin_amdgcn_sqrtf(fmaf(gx, gx, fmaf(gy, gy, 1e-8f)));
    bool neg = gy < 0.f;
    float fx = neg ? -gx : gx;
    float fy = neg ? -gy : gy;
    float u, v;
    u = 0.17364817766693033f * fx; v = 0.984807753012208f * fy;
    acc[0] += (u <= v) ? mag : 0.f;
    acc[8] += (u <= -v) ? mag : 0.f;
    u = 0.5f * fx; v = 0.8660254037844387f * fy;
    acc[1] += (u <= v) ? mag : 0.f;
    acc[7] += (u <= -v) ? mag : 0.f;
    u = 0.766044443118978f * fx; v = 0.6427876096865393f * fy;
    acc[2] += (u <= v) ? mag : 0.f;
    acc[6] += (u <= -v) ? mag : 0.f;
    u = 0.9396926207859084f * fx; v = 0.3420201433256687f * fy;
    acc[3] += (u <= v) ? mag : 0.f;
    acc[5] += (u <= -v) ? mag : 0.f;
    acc[4] += (fx <= 0.f) ? mag : 0.f;
    acc[9] += mag;
  }
}

// one x row (8 floats, window cols gc0-2..gc0+5) from global, zero-filled OOB
__device__ __forceinline__ void load_grow(const float* __restrict__ xim, int gr, bool valid,
                                          int o0, int o1, int o2, int o3,
                                          float mlo, float mhi, float r[8]) {
  if (valid) {
    const float* p = xim + gr * W_IMG;
    float2 a = *reinterpret_cast<const float2*>(p + o0);
    float2 b = *reinterpret_cast<const float2*>(p + o1);
    float2 c = *reinterpret_cast<const float2*>(p + o2);
    float2 d = *reinterpret_cast<const float2*>(p + o3);
    r[0] = a.x * mlo; r[1] = a.y * mlo;
    r[2] = b.x;       r[3] = b.y;
    r[4] = c.x;       r[5] = c.y;
    r[6] = d.x * mhi; r[7] = d.y * mhi;
  } else {
#pragma unroll
    for (int i = 0; i < 8; ++i) r[i] = 0.f;
  }
}

__global__ __launch_bounds__(256, 4) void phog_hist_kernel(const float* __restrict__ x,
                                                           float* __restrict__ hist2) {
  const int tile = blockIdx.x;  // 0..7: (tr2=tile>>2 in 0..1, tc=tile&3 in 0..3)
  const int bc = blockIdx.y;    // 0..511
  const int tr2 = tile >> 2;
  const int tc = tile & 3;
  const int R0 = tr2 * 128;     // block covers rows R0..R0+127 (2 cells)
  const int C0 = tc * 64;
  const int tid = threadIdx.x;
  const int tcol = tid & 15;    // 0..15 -> 4 cols each
  const int trow = tid >> 4;    // 0..15 -> 8 rows each

  const float* xim = x + (size_t)bc * (H_IMG * W_IMG);

  const int gr0 = R0 + 8 * trow;  // first output row
  const int gc0 = C0 + 4 * tcol;  // first output col
  const int bcol = gc0 - 2;       // window col 0 (global)

  // clamped float2 offsets + masks for the 2 edge float2s
  const int o0 = (bcol < 0) ? 0 : bcol;
  const int o1 = gc0;
  const int o2 = gc0 + 2;
  const int o3 = (gc0 + 4 > 254) ? 254 : (gc0 + 4);
  const float mlo = (bcol >= 0) ? 1.f : 0.f;          // cols gc0-2,gc0-1
  const float mhi = (gc0 + 5 <= 255) ? 1.f : 0.f;     // cols gc0+4,gc0+5

  const bool vlo = gr0 > 0;     // x rows gr0-2, gr0-1 valid?
  const bool vhi = gr0 < 248;   // x rows gr0+8, gr0+9 valid?
  const float rm_first = vlo ? 1.f : 0.f;  // lap row gr0-1
  const float rm_last = vhi ? 1.f : 0.f;   // lap row gr0+8
  const float wm0 = (gc0 >= 1) ? 1.f : 0.f;        // lap col gc0-1
  const float wm5 = (gc0 + 4 <= 255) ? 1.f : 0.f;  // lap col gc0+4

  float acc[10];
#pragma unroll
  for (int k = 0; k < 10; ++k) acc[k] = 0.f;

  float xr0[8], xr1[8], xr2[8], lA[6], lB[6], lC[6];

  // x window rows: i=0..11 at global row gr0-2+i
  load_grow(xim, gr0 - 2, vlo, o0, o1, o2, o3, mlo, mhi, xr0);
  load_grow(xim, gr0 - 1, vlo, o0, o1, o2, o3, mlo, mhi, xr1);
  load_grow(xim, gr0 + 0, true, o0, o1, o2, o3, mlo, mhi, xr2);
  lap_row6(lA, xr0, xr1, xr2, wm0, wm5, rm_first);   // lap 0
  load_grow(xim, gr0 + 1, true, o0, o1, o2, o3, mlo, mhi, xr0);
  lap_row6(lB, xr1, xr2, xr0, wm0, wm5, 1.f);        // lap 1
  load_grow(xim, gr0 + 2, true, o0, o1, o2, o3, mlo, mhi, xr1);
  lap_row6(lC, xr2, xr0, xr1, wm0, wm5, 1.f);        // lap 2
  out_row4(lA, lB, lC, acc);                         // out 0
  load_grow(xim, gr0 + 3, true, o0, o1, o2, o3, mlo, mhi, xr2);
  lap_row6(lA, xr0, xr1, xr2, wm0, wm5, 1.f);        // lap 3
  out_row4(lB, lC, lA, acc);                         // out 1
  load_grow(xim, gr0 + 4, true, o0, o1, o2, o3, mlo, mhi, xr0);
  lap_row6(lB, xr1, xr2, xr0, wm0, wm5, 1.f);        // lap 4
  out_row4(lC, lA, lB, acc);                         // out 2
  load_grow(xim, gr0 + 5, true, o0, o1, o2, o3, mlo, mhi, xr1);
  lap_row6(lC, xr2, xr0, xr1, wm0, wm5, 1.f);        // lap 5
  out_row4(lA, lB, lC, acc);                         // out 3
  load_grow(xim, gr0 + 6, true, o0, o1, o2, o3, mlo, mhi, xr2);
  lap_row6(lA, xr0, xr1, xr2, wm0, wm5, 1.f);        // lap 6
  out_row4(lB, lC, lA, acc);                         // out 4
  load_grow(xim, gr0 + 7, true, o0, o1, o2, o3, mlo, mhi, xr0);
  lap_row6(lB, xr1, xr2, xr0, wm0, wm5, 1.f);        // lap 7
  out_row4(lC, lA, lB, acc);                         // out 5
  load_grow(xim, gr0 + 8, vhi, o0, o1, o2, o3, mlo, mhi, xr1);
  lap_row6(lC, xr2, xr0, xr1, wm0, wm5, 1.f);        // lap 8
  out_row4(lA, lB, lC, acc);                         // out 6
  load_grow(xim, gr0 + 9, vhi, o0, o1, o2, o3, mlo, mhi, xr2);
  lap_row6(lA, xr0, xr1, xr2, wm0, wm5, rm_last);    // lap 9
  out_row4(lB, lC, lA, acc);                         // out 7

  // wave reduce (64 lanes; each wave lies entirely within one cell)
#pragma unroll
  for (int k = 0; k < 10; ++k) {
    float v = acc[k];
#pragma unroll
    for (int off = 32; off > 0; off >>= 1) v += __shfl_xor(v, off);
    acc[k] = v;
  }

  __shared__ float hred[4][10];
  __shared__ float hs[2][10];
  int lane = tid & 63;
  int wave = tid >> 6;
  if (lane == 0) {
#pragma unroll
    for (int k = 0; k < 10; ++k) hred[wave][k] = acc[k];
  }
  __syncthreads();
  if (tid < 10) hs[0][tid] = hred[0][tid] + hred[1][tid];
  if (tid >= 32 && tid < 42) hs[1][tid - 32] = hred[2][tid - 32] + hred[3][tid - 32];
  __syncthreads();

  const int cell_top = (2 * tr2) * 4 + tc;
  const int cell_bot = (2 * tr2 + 1) * 4 + tc;
  if (tid < 9) {
    float h = (tid == 0) ? ((hs[0][9] - hs[0][0]) + hs[0][8]) : (hs[0][tid - 1] - hs[0][tid]);
    hist2[(bc * 16 + cell_top) * 9 + tid] = h;
  }
  if (tid >= 32 && tid < 41) {
    int k = tid - 32;
    float h = (k == 0) ? ((hs[1][9] - hs[1][0]) + hs[1][8]) : (hs[1][k - 1] - hs[1][k]);
    hist2[(bc * 16 + cell_bot) * 9 + k] = h;
  }
}

__global__ __launch_bounds__(256) void phog_norm_kernel(const float* __restrict__ hist2,
                                                        float* __restrict__ out) {
  int t = blockIdx.x * 256 + threadIdx.x;
  if (t >= 32 * 336) return;
  int b = t / 336;
  int r = t - b * 336;

  float h[9];
  if (r < 16) {
    const float* p = hist2 + (b * 16 + r) * 144;
#pragma unroll
    for (int k = 0; k < 9; ++k) {
      float s = 0.f;
#pragma unroll
      for (int cell = 0; cell < 16; ++cell) s += p[cell * 9 + k];
      h[k] = s;
    }
  } else if (r < 80) {
    int q = r - 16;
    int c = q >> 2;
    int cell = q & 3;
    int r1 = cell >> 1, c1 = cell & 1;
    const float* p = hist2 + (b * 16 + c) * 144;
    int i00 = ((2 * r1) * 4 + 2 * c1) * 9;
    int i01 = ((2 * r1) * 4 + 2 * c1 + 1) * 9;
    int i10 = ((2 * r1 + 1) * 4 + 2 * c1) * 9;
    int i11 = ((2 * r1 + 1) * 4 + 2 * c1 + 1) * 9;
#pragma unroll
    for (int k = 0; k < 9; ++k) h[k] = (p[i00 + k] + p[i01 + k]) + (p[i10 + k] + p[i11 + k]);
  } else {
    int q = r - 80;
    int c = q >> 4;
    int cell = q & 15;
    const float* p = hist2 + ((b * 16 + c) * 16 + cell) * 9;
#pragma unroll
    for (int k = 0; k < 9; ++k) h[k] = p[k];
  }

  float s = 0.f;
#pragma unroll
  for (int k = 0; k < 9; ++k) s += h[k];
  float inv = 1.f / (s + 1e-8f);
#pragma unroll
  for (int k = 0; k < 9; ++k) h[k] *= inv;
  float n2 = 0.f;
#pragma unroll
  for (int k = 0; k < 9; ++k) n2 = fmaf(h[k], h[k], n2);
  float nrm = sqrtf(n2);
  float inv2 = 1.f / fmaxf(nrm, 1e-12f);
#pragma unroll
  for (int k = 0; k < 9; ++k) out[t * 9 + k] = h[k] * inv2;
}

extern "C" void kernel_launch(void* const* d_in, const int* in_sizes, int n_in,
                              void* d_out, int out_size, void* d_ws, size_t ws_size,
                              hipStream_t stream) {
  const float* x = (const float*)d_in[0];
  float* out = (float*)d_out;
  float* hist2 = (float*)d_ws;  // 512*16*9 floats = 294912 B

  dim3 g1(8, 512);
  phog_hist_kernel<<<g1, 256, 0, stream>>>(x, hist2);

  int total = 32 * 336;
  phog_norm_kernel<<<(total + 255) / 256, 256, 0, stream>>>(hist2, out);
}

// Round 5
// 76.191 us; speedup vs baseline: 3.3783x; 1.3591x over previous
//
#include <hip/hip_runtime.h>
#include <hip/hip_bf16.h>

// PHOG: lap = dw3x3(x, laplacian); gx,gy = dw3x3(lap, sobel); mag/ang -> 9-bin
// hist over pyramid cells (1+4+16), L1-ish then L2 normalize.
//
// R5 = R4 with the occupancy hint REMOVED. History: (256,5) capped VGPR at 48
// (full spill, 579MB scratch); (256,4) still made the allocator pick 64 VGPR
// and spill 172MB. Plain __launch_bounds__(256) lets the allocator avoid
// spill first (cf. m97: 164 VGPR no-spill with plain bounds). Structure:
// no LDS staging; each thread computes a 4w x 8t output tile straight from
// global (12 rows x 4 float2); L1/L2 serve the 3x window overlap.
// Cumulative-histogram binning (verified absmax 2e-3).

#define H_IMG 256
#define W_IMG 256

__device__ __forceinline__ void lap_row6(float dst[6], const float u[8], const float m[8],
                                         const float d[8], float wm0, float wm5, float rowm) {
#pragma unroll
  for (int c = 0; c < 6; ++c) {
    float v = (u[c + 1] + d[c + 1]) + fmaf(-4.f, m[c + 1], m[c] + m[c + 2]);
    dst[c] = v * rowm;
  }
  dst[0] *= wm0;
  dst[5] *= wm5;
}

// gradient + cumulative-binning for one output row (4 px) from lap rows A,B,C
// acc[0..8] = sums of mag where ang >= b_i (monotone boundaries), acc[9] = total
__device__ __forceinline__ void out_row4(const float A[6], const float B[6], const float C[6],
                                         float acc[10]) {
  float cs[6], dd[6];
#pragma unroll
  for (int c = 0; c < 6; ++c) {
    cs[c] = A[c] + fmaf(2.f, B[c], C[c]);
    dd[c] = C[c] - A[c];
  }
#pragma unroll
  for (int c = 0; c < 4; ++c) {
    float gx = cs[c + 2] - cs[c];
    float gy = fmaf(2.f, dd[c + 1], dd[c] + dd[c + 2]);
    float mag = __builtin_amdgcn_sqrtf(fmaf(gx, gx, fmaf(gy, gy, 1e-8f)));
    bool neg = gy < 0.f;
    float fx = neg ? -gx : gx;
    float fy = neg ? -gy : gy;
    float u, v;
    u = 0.17364817766693033f * fx; v = 0.984807753012208f * fy;
    acc[0] += (u <= v) ? mag : 0.f;
    acc[8] += (u <= -v) ? mag : 0.f;
    u = 0.5f * fx; v = 0.8660254037844387f * fy;
    acc[1] += (u <= v) ? mag : 0.f;
    acc[7] += (u <= -v) ? mag : 0.f;
    u = 0.766044443118978f * fx; v = 0.6427876096865393f * fy;
    acc[2] += (u <= v) ? mag : 0.f;
    acc[6] += (u <= -v) ? mag : 0.f;
    u = 0.9396926207859084f * fx; v = 0.3420201433256687f * fy;
    acc[3] += (u <= v) ? mag : 0.f;
    acc[5] += (u <= -v) ? mag : 0.f;
    acc[4] += (fx <= 0.f) ? mag : 0.f;
    acc[9] += mag;
  }
}

// one x row (8 floats, window cols gc0-2..gc0+5) from global, zero-filled OOB
__device__ __forceinline__ void load_grow(const float* __restrict__ xim, int gr, bool valid,
                                          int o0, int o1, int o2, int o3,
                                          float mlo, float mhi, float r[8]) {
  if (valid) {
    const float* p = xim + gr * W_IMG;
    float2 a = *reinterpret_cast<const float2*>(p + o0);
    float2 b = *reinterpret_cast<const float2*>(p + o1);
    float2 c = *reinterpret_cast<const float2*>(p + o2);
    float2 d = *reinterpret_cast<const float2*>(p + o3);
    r[0] = a.x * mlo; r[1] = a.y * mlo;
    r[2] = b.x;       r[3] = b.y;
    r[4] = c.x;       r[5] = c.y;
    r[6] = d.x * mhi; r[7] = d.y * mhi;
  } else {
#pragma unroll
    for (int i = 0; i < 8; ++i) r[i] = 0.f;
  }
}

__global__ __launch_bounds__(256) void phog_hist_kernel(const float* __restrict__ x,
                                                        float* __restrict__ hist2) {
  const int tile = blockIdx.x;  // 0..7: (tr2=tile>>2 in 0..1, tc=tile&3 in 0..3)
  const int bc = blockIdx.y;    // 0..511
  const int tr2 = tile >> 2;
  const int tc = tile & 3;
  const int R0 = tr2 * 128;     // block covers rows R0..R0+127 (2 cells)
  const int C0 = tc * 64;
  const int tid = threadIdx.x;
  const int tcol = tid & 15;    // 0..15 -> 4 cols each
  const int trow = tid >> 4;    // 0..15 -> 8 rows each

  const float* xim = x + (size_t)bc * (H_IMG * W_IMG);

  const int gr0 = R0 + 8 * trow;  // first output row
  const int gc0 = C0 + 4 * tcol;  // first output col
  const int bcol = gc0 - 2;       // window col 0 (global)

  // clamped float2 offsets + masks for the 2 edge float2s
  const int o0 = (bcol < 0) ? 0 : bcol;
  const int o1 = gc0;
  const int o2 = gc0 + 2;
  const int o3 = (gc0 + 4 > 254) ? 254 : (gc0 + 4);
  const float mlo = (bcol >= 0) ? 1.f : 0.f;          // cols gc0-2,gc0-1
  const float mhi = (gc0 + 5 <= 255) ? 1.f : 0.f;     // cols gc0+4,gc0+5

  const bool vlo = gr0 > 0;     // x rows gr0-2, gr0-1 valid?
  const bool vhi = gr0 < 248;   // x rows gr0+8, gr0+9 valid?
  const float rm_first = vlo ? 1.f : 0.f;  // lap row gr0-1
  const float rm_last = vhi ? 1.f : 0.f;   // lap row gr0+8
  const float wm0 = (gc0 >= 1) ? 1.f : 0.f;        // lap col gc0-1
  const float wm5 = (gc0 + 4 <= 255) ? 1.f : 0.f;  // lap col gc0+4

  float acc[10];
#pragma unroll
  for (int k = 0; k < 10; ++k) acc[k] = 0.f;

  float xr0[8], xr1[8], xr2[8], lA[6], lB[6], lC[6];

  // x window rows: i=0..11 at global row gr0-2+i
  load_grow(xim, gr0 - 2, vlo, o0, o1, o2, o3, mlo, mhi, xr0);
  load_grow(xim, gr0 - 1, vlo, o0, o1, o2, o3, mlo, mhi, xr1);
  load_grow(xim, gr0 + 0, true, o0, o1, o2, o3, mlo, mhi, xr2);
  lap_row6(lA, xr0, xr1, xr2, wm0, wm5, rm_first);   // lap 0
  load_grow(xim, gr0 + 1, true, o0, o1, o2, o3, mlo, mhi, xr0);
  lap_row6(lB, xr1, xr2, xr0, wm0, wm5, 1.f);        // lap 1
  load_grow(xim, gr0 + 2, true, o0, o1, o2, o3, mlo, mhi, xr1);
  lap_row6(lC, xr2, xr0, xr1, wm0, wm5, 1.f);        // lap 2
  out_row4(lA, lB, lC, acc);                         // out 0
  load_grow(xim, gr0 + 3, true, o0, o1, o2, o3, mlo, mhi, xr2);
  lap_row6(lA, xr0, xr1, xr2, wm0, wm5, 1.f);        // lap 3
  out_row4(lB, lC, lA, acc);                         // out 1
  load_grow(xim, gr0 + 4, true, o0, o1, o2, o3, mlo, mhi, xr0);
  lap_row6(lB, xr1, xr2, xr0, wm0, wm5, 1.f);        // lap 4
  out_row4(lC, lA, lB, acc);                         // out 2
  load_grow(xim, gr0 + 5, true, o0, o1, o2, o3, mlo, mhi, xr1);
  lap_row6(lC, xr2, xr0, xr1, wm0, wm5, 1.f);        // lap 5
  out_row4(lA, lB, lC, acc);                         // out 3
  load_grow(xim, gr0 + 6, true, o0, o1, o2, o3, mlo, mhi, xr2);
  lap_row6(lA, xr0, xr1, xr2, wm0, wm5, 1.f);        // lap 6
  out_row4(lB, lC, lA, acc);                         // out 4
  load_grow(xim, gr0 + 7, true, o0, o1, o2, o3, mlo, mhi, xr0);
  lap_row6(lB, xr1, xr2, xr0, wm0, wm5, 1.f);        // lap 7
  out_row4(lC, lA, lB, acc);                         // out 5
  load_grow(xim, gr0 + 8, vhi, o0, o1, o2, o3, mlo, mhi, xr1);
  lap_row6(lC, xr2, xr0, xr1, wm0, wm5, 1.f);        // lap 8
  out_row4(lA, lB, lC, acc);                         // out 6
  load_grow(xim, gr0 + 9, vhi, o0, o1, o2, o3, mlo, mhi, xr2);
  lap_row6(lA, xr0, xr1, xr2, wm0, wm5, rm_last);    // lap 9
  out_row4(lB, lC, lA, acc);                         // out 7

  // wave reduce (64 lanes; each wave lies entirely within one cell)
#pragma unroll
  for (int k = 0; k < 10; ++k) {
    float v = acc[k];
#pragma unroll
    for (int off = 32; off > 0; off >>= 1) v += __shfl_xor(v, off);
    acc[k] = v;
  }

  __shared__ float hred[4][10];
  __shared__ float hs[2][10];
  int lane = tid & 63;
  int wave = tid >> 6;
  if (lane == 0) {
#pragma unroll
    for (int k = 0; k < 10; ++k) hred[wave][k] = acc[k];
  }
  __syncthreads();
  if (tid < 10) hs[0][tid] = hred[0][tid] + hred[1][tid];
  if (tid >= 32 && tid < 42) hs[1][tid - 32] = hred[2][tid - 32] + hred[3][tid - 32];
  __syncthreads();

  const int cell_top = (2 * tr2) * 4 + tc;
  const int cell_bot = (2 * tr2 + 1) * 4 + tc;
  if (tid < 9) {
    float h = (tid == 0) ? ((hs[0][9] - hs[0][0]) + hs[0][8]) : (hs[0][tid - 1] - hs[0][tid]);
    hist2[(bc * 16 + cell_top) * 9 + tid] = h;
  }
  if (tid >= 32 && tid < 41) {
    int k = tid - 32;
    float h = (k == 0) ? ((hs[1][9] - hs[1][0]) + hs[1][8]) : (hs[1][k - 1] - hs[1][k]);
    hist2[(bc * 16 + cell_bot) * 9 + k] = h;
  }
}

__global__ __launch_bounds__(256) void phog_norm_kernel(const float* __restrict__ hist2,
                                                        float* __restrict__ out) {
  int t = blockIdx.x * 256 + threadIdx.x;
  if (t >= 32 * 336) return;
  int b = t / 336;
  int r = t - b * 336;

  float h[9];
  if (r < 16) {
    const float* p = hist2 + (b * 16 + r) * 144;
#pragma unroll
    for (int k = 0; k < 9; ++k) {
      float s = 0.f;
#pragma unroll
      for (int cell = 0; cell < 16; ++cell) s += p[cell * 9 + k];
      h[k] = s;
    }
  } else if (r < 80) {
    int q = r - 16;
    int c = q >> 2;
    int cell = q & 3;
    int r1 = cell >> 1, c1 = cell & 1;
    const float* p = hist2 + (b * 16 + c) * 144;
    int i00 = ((2 * r1) * 4 + 2 * c1) * 9;
    int i01 = ((2 * r1) * 4 + 2 * c1 + 1) * 9;
    int i10 = ((2 * r1 + 1) * 4 + 2 * c1) * 9;
    int i11 = ((2 * r1 + 1) * 4 + 2 * c1 + 1) * 9;
#pragma unroll
    for (int k = 0; k < 9; ++k) h[k] = (p[i00 + k] + p[i01 + k]) + (p[i10 + k] + p[i11 + k]);
  } else {
    int q = r - 80;
    int c = q >> 4;
    int cell = q & 15;
    const float* p = hist2 + ((b * 16 + c) * 16 + cell) * 9;
#pragma unroll
    for (int k = 0; k < 9; ++k) h[k] = p[k];
  }

  float s = 0.f;
#pragma unroll
  for (int k = 0; k < 9; ++k) s += h[k];
  float inv = 1.f / (s + 1e-8f);
#pragma unroll
  for (int k = 0; k < 9; ++k) h[k] *= inv;
  float n2 = 0.f;
#pragma unroll
  for (int k = 0; k < 9; ++k) n2 = fmaf(h[k], h[k], n2);
  float nrm = sqrtf(n2);
  float inv2 = 1.f / fmaxf(nrm, 1e-12f);
#pragma unroll
  for (int k = 0; k < 9; ++k) out[t * 9 + k] = h[k] * inv2;
}

extern "C" void kernel_launch(void* const* d_in, const int* in_sizes, int n_in,
                              void* d_out, int out_size, void* d_ws, size_t ws_size,
                              hipStream_t stream) {
  const float* x = (const float*)d_in[0];
  float* out = (float*)d_out;
  float* hist2 = (float*)d_ws;  // 512*16*9 floats = 294912 B

  dim3 g1(8, 512);
  phog_hist_kernel<<<g1, 256, 0, stream>>>(x, hist2);

  int total = 32 * 336;
  phog_norm_kernel<<<(total + 255) / 256, 256, 0, stream>>>(hist2, out);
}

// Round 6
// 71.111 us; speedup vs baseline: 3.6197x; 1.0714x over previous
//
#include <hip/hip_runtime.h>

// PHOG: lap = dw3x3(x, laplacian); gx,gy = dw3x3(lap, sobel); mag/ang -> 9-bin
// hist over pyramid cells (1+4+16), L1-ish then L2 normalize.
//
// R6: async-staged LDS version. One block per (bc, 64x64 cell). Stage the
// 68-row x 80-float x-window into LDS via global_load_lds (16B, no VGPR
// roundtrip, all loads in flight at once) -> barrier -> compute from LDS.
// ~22KB LDS -> ~5-7 blocks/CU; cross-block overlap hides the staging drain
// (R5 diagnosis: latency-stall-bound, nothing busy). XCD-swizzle keeps all
// 16 cells of a bc-image on one XCD's L2 for halo re-reads.
// Cumulative-histogram binning identical to R2..R5 (verified absmax 2e-3).

#define H_IMG 256
#define W_IMG 256

#define AS3 __attribute__((address_space(3)))
#define AS1 __attribute__((address_space(1)))

// lap row from x rows u (above), m (center), d (below); masks zero lap outside image
__device__ __forceinline__ void lap_row6(float dst[6], const float u[8], const float m[8],
                                         const float d[8], float wm0, float wm5, float rowm) {
#pragma unroll
  for (int c = 0; c < 6; ++c) {
    float v = (u[c + 1] + d[c + 1]) + fmaf(-4.f, m[c + 1], m[c] + m[c + 2]);
    dst[c] = v * rowm;
  }
  dst[0] *= wm0;
  dst[5] *= wm5;
}

// gradient + cumulative-binning for one output row (4 px) from lap rows A,B,C
// acc[0..8] = sums of mag where ang >= b_i (monotone boundaries), acc[9] = total
__device__ __forceinline__ void out_row4(const float A[6], const float B[6], const float C[6],
                                         float acc[10]) {
  float cs[6], dd[6];
#pragma unroll
  for (int c = 0; c < 6; ++c) {
    cs[c] = A[c] + fmaf(2.f, B[c], C[c]);
    dd[c] = C[c] - A[c];
  }
#pragma unroll
  for (int c = 0; c < 4; ++c) {
    float gx = cs[c + 2] - cs[c];
    float gy = fmaf(2.f, dd[c + 1], dd[c] + dd[c + 2]);
    float mag = __builtin_amdgcn_sqrtf(fmaf(gx, gx, fmaf(gy, gy, 1e-8f)));
    bool neg = gy < 0.f;
    float fx = neg ? -gx : gx;
    float fy = neg ? -gy : gy;
    float u, v;
    u = 0.17364817766693033f * fx; v = 0.984807753012208f * fy;
    acc[0] += (u <= v) ? mag : 0.f;
    acc[8] += (u <= -v) ? mag : 0.f;
    u = 0.5f * fx; v = 0.8660254037844387f * fy;
    acc[1] += (u <= v) ? mag : 0.f;
    acc[7] += (u <= -v) ? mag : 0.f;
    u = 0.766044443118978f * fx; v = 0.6427876096865393f * fy;
    acc[2] += (u <= v) ? mag : 0.f;
    acc[6] += (u <= -v) ? mag : 0.f;
    u = 0.9396926207859084f * fx; v = 0.3420201433256687f * fy;
    acc[3] += (u <= v) ? mag : 0.f;
    acc[5] += (u <= -v) ? mag : 0.f;
    acc[4] += (fx <= 0.f) ? mag : 0.f;
    acc[9] += mag;
  }
}

// one x row (8 floats: window cols gc0-2..gc0+5) from the LDS tile.
// Row layout: 80 floats, position p <-> global col C0-4+p.
// Window = positions [4t+2, 4t+10): b128@4t (use .z,.w) + b128@4t+4 + b64@4t+8.
__device__ __forceinline__ void read_xrow(const float* xs, int tr, int p0,
                                          float mlo, float mhi, bool valid, float r[8]) {
  if (valid) {
    const float* rowp = xs + tr * 80 + p0;
    float4 a = *reinterpret_cast<const float4*>(rowp);
    float4 b = *reinterpret_cast<const float4*>(rowp + 4);
    float2 c = *reinterpret_cast<const float2*>(rowp + 8);
    r[0] = a.z * mlo; r[1] = a.w * mlo;
    r[2] = b.x;       r[3] = b.y;
    r[4] = b.z;       r[5] = b.w;
    r[6] = c.x * mhi; r[7] = c.y * mhi;
  } else {
#pragma unroll
    for (int i = 0; i < 8; ++i) r[i] = 0.f;
  }
}

__global__ __launch_bounds__(256) void phog_hist_kernel(const float* __restrict__ x,
                                                        float* __restrict__ hist2) {
  // XCD swizzle: give each XCD 64 whole bc-images (16 cells contiguous).
  const int f = blockIdx.y * 16 + blockIdx.x;   // 0..8191, HW xcd ~ f%8
  const int xcd = f & 7;
  const int idx = f >> 3;                       // 0..1023 within xcd
  const int bc = xcd * 64 + (idx >> 4);
  const int tile = idx & 15;                    // cell id (tr*4+tc)
  const int R0 = (tile >> 2) * 64;
  const int C0 = (tile & 3) * 64;
  const int tid = threadIdx.x;

  __shared__ float xs[68 * 80];                 // rows R0-2..R0+65, cols C0-4..C0+75
  __shared__ float hred[4][10];
  __shared__ float hsum[10];

  const float* xim = x + (size_t)bc * (H_IMG * W_IMG);

  // ---- async stage: 68 rows x 20 float4-slots = 1360 slots, 6 iters of 256.
  // OOB sources clamped (garbage staged); consumption masks zero them.
  const int wavebase = tid & 192;               // wave*64 (slot base is wave-uniform)
  for (int i = 0; i < 6; ++i) {
    int slot = tid + i * 256;
    if (slot < 1360) {
      int row = slot / 20;
      int c4 = slot - row * 20;
      int gr = R0 - 2 + row;
      gr = gr < 0 ? 0 : (gr > 255 ? 255 : gr);
      int gc = C0 - 4 + 4 * c4;
      gc = gc < 0 ? 0 : (gc > 252 ? 252 : gc);
      __builtin_amdgcn_global_load_lds((const AS1 void*)(xim + gr * W_IMG + gc),
                                       (AS3 void*)(xs + (wavebase + i * 256) * 4),
                                       16, 0, 0);
    }
  }
  __syncthreads();  // drains vmcnt

  // ---- compute: 4 cols x 4 rows per thread
  const int tcol = tid & 15;
  const int trow = tid >> 4;
  const int gr0 = R0 + 4 * trow;   // first output row
  const int gc0 = C0 + 4 * tcol;   // first output col
  const int p0 = 4 * tcol;         // LDS row position of global col gc0-4

  const float mlo = (gc0 - 2 >= 0) ? 1.f : 0.f;     // x cols gc0-2,gc0-1
  const float mhi = (gc0 + 5 <= 255) ? 1.f : 0.f;   // x cols gc0+4,gc0+5
  const float wm0 = (gc0 >= 1) ? 1.f : 0.f;         // lap col gc0-1
  const float wm5 = (gc0 + 4 <= 255) ? 1.f : 0.f;   // lap col gc0+4
  const bool vlo = gr0 > 0;       // x rows gr0-2, gr0-1 valid
  const bool vhi = gr0 < 252;     // x rows gr0+4, gr0+5 valid
  const float rm_first = (gr0 >= 1) ? 1.f : 0.f;    // lap row gr0-1
  const float rm_last = (gr0 + 4 <= 255) ? 1.f : 0.f;  // lap row gr0+4

  float acc[10];
#pragma unroll
  for (int k = 0; k < 10; ++k) acc[k] = 0.f;

  float xr0[8], xr1[8], xr2[8], lA[6], lB[6], lC[6];
  const int tr0 = 4 * trow;  // LDS tile row of x row gr0-2

  read_xrow(xs, tr0 + 0, p0, mlo, mhi, vlo, xr0);
  read_xrow(xs, tr0 + 1, p0, mlo, mhi, vlo, xr1);
  read_xrow(xs, tr0 + 2, p0, mlo, mhi, true, xr2);
  lap_row6(lA, xr0, xr1, xr2, wm0, wm5, rm_first);   // lap gr0-1
  read_xrow(xs, tr0 + 3, p0, mlo, mhi, true, xr0);
  lap_row6(lB, xr1, xr2, xr0, wm0, wm5, 1.f);        // lap gr0
  read_xrow(xs, tr0 + 4, p0, mlo, mhi, true, xr1);
  lap_row6(lC, xr2, xr0, xr1, wm0, wm5, 1.f);        // lap gr0+1
  out_row4(lA, lB, lC, acc);                         // out gr0
  read_xrow(xs, tr0 + 5, p0, mlo, mhi, true, xr2);
  lap_row6(lA, xr0, xr1, xr2, wm0, wm5, 1.f);        // lap gr0+2
  out_row4(lB, lC, lA, acc);                         // out gr0+1
  read_xrow(xs, tr0 + 6, p0, mlo, mhi, vhi, xr0);
  lap_row6(lB, xr1, xr2, xr0, wm0, wm5, 1.f);        // lap gr0+3
  out_row4(lC, lA, lB, acc);                         // out gr0+2
  read_xrow(xs, tr0 + 7, p0, mlo, mhi, vhi, xr1);
  lap_row6(lC, xr2, xr0, xr1, wm0, wm5, rm_last);    // lap gr0+4
  out_row4(lA, lB, lC, acc);                         // out gr0+3

  // ---- reduce: wave butterfly, then cross-wave via LDS
#pragma unroll
  for (int k = 0; k < 10; ++k) {
    float v = acc[k];
#pragma unroll
    for (int off = 32; off > 0; off >>= 1) v += __shfl_xor(v, off);
    acc[k] = v;
  }
  const int lane = tid & 63;
  const int wave = tid >> 6;
  if (lane == 0) {
#pragma unroll
    for (int k = 0; k < 10; ++k) hred[wave][k] = acc[k];
  }
  __syncthreads();
  if (tid < 10) hsum[tid] = (hred[0][tid] + hred[1][tid]) + (hred[2][tid] + hred[3][tid]);
  __syncthreads();
  if (tid < 9) {
    float h = (tid == 0) ? ((hsum[9] - hsum[0]) + hsum[8]) : (hsum[tid - 1] - hsum[tid]);
    hist2[(bc * 16 + tile) * 9 + tid] = h;
  }
}

__global__ __launch_bounds__(256) void phog_norm_kernel(const float* __restrict__ hist2,
                                                        float* __restrict__ out) {
  int t = blockIdx.x * 256 + threadIdx.x;
  if (t >= 32 * 336) return;
  int b = t / 336;
  int r = t - b * 336;

  float h[9];
  if (r < 16) {
    const float* p = hist2 + (b * 16 + r) * 144;
#pragma unroll
    for (int k = 0; k < 9; ++k) {
      float s = 0.f;
#pragma unroll
      for (int cell = 0; cell < 16; ++cell) s += p[cell * 9 + k];
      h[k] = s;
    }
  } else if (r < 80) {
    int q = r - 16;
    int c = q >> 2;
    int cell = q & 3;
    int r1 = cell >> 1, c1 = cell & 1;
    const float* p = hist2 + (b * 16 + c) * 144;
    int i00 = ((2 * r1) * 4 + 2 * c1) * 9;
    int i01 = ((2 * r1) * 4 + 2 * c1 + 1) * 9;
    int i10 = ((2 * r1 + 1) * 4 + 2 * c1) * 9;
    int i11 = ((2 * r1 + 1) * 4 + 2 * c1 + 1) * 9;
#pragma unroll
    for (int k = 0; k < 9; ++k) h[k] = (p[i00 + k] + p[i01 + k]) + (p[i10 + k] + p[i11 + k]);
  } else {
    int q = r - 80;
    int c = q >> 4;
    int cell = q & 15;
    const float* p = hist2 + ((b * 16 + c) * 16 + cell) * 9;
#pragma unroll
    for (int k = 0; k < 9; ++k) h[k] = p[k];
  }

  float s = 0.f;
#pragma unroll
  for (int k = 0; k < 9; ++k) s += h[k];
  float inv = 1.f / (s + 1e-8f);
#pragma unroll
  for (int k = 0; k < 9; ++k) h[k] *= inv;
  float n2 = 0.f;
#pragma unroll
  for (int k = 0; k < 9; ++k) n2 = fmaf(h[k], h[k], n2);
  float nrm = sqrtf(n2);
  float inv2 = 1.f / fmaxf(nrm, 1e-12f);
#pragma unroll
  for (int k = 0; k < 9; ++k) out[t * 9 + k] = h[k] * inv2;
}

extern "C" void kernel_launch(void* const* d_in, const int* in_sizes, int n_in,
                              void* d_out, int out_size, void* d_ws, size_t ws_size,
                              hipStream_t stream) {
  const float* x = (const float*)d_in[0];
  float* out = (float*)d_out;
  float* hist2 = (float*)d_ws;  // 512*16*9 floats = 294912 B

  dim3 g1(16, 512);
  phog_hist_kernel<<<g1, 256, 0, stream>>>(x, hist2);

  int total = 32 * 336;
  phog_norm_kernel<<<(total + 255) / 256, 256, 0, stream>>>(hist2, out);
}

// Round 7
// 64.972 us; speedup vs baseline: 3.9617x; 1.0945x over previous
//
#include <hip/hip_runtime.h>

// PHOG: lap = dw3x3(x, laplacian); gx,gy = dw3x3(lap, sobel); mag/ang -> 9-bin
// hist over pyramid cells (1+4+16), L1-ish then L2 normalize.
//
// R7: register-upfront version. No LDS staging at all. Each thread loads its
// FULL 8-row x 8-col x-window into registers first (32 independent
// global_load_dwordx2 -> MLP=32, no WAR chain; compiler emits partial vmcnt
// waits so lap/out compute overlaps the remaining loads), then computes
// 4x4 output pixels. R5's rolling buffers had MLP~3 (latency-bound, 93us);
// R6's LDS staging phase-locked on barrier+vmcnt(0) (~70us, 38% real VALU).
// Arithmetic floor ~28us. Binning math unchanged (verified absmax 2e-3).

#define H_IMG 256
#define W_IMG 256

__device__ __forceinline__ void lap_row6(float dst[6], const float u[8], const float m[8],
                                         const float d[8], float wm0, float wm5, float rowm) {
#pragma unroll
  for (int c = 0; c < 6; ++c) {
    float v = (u[c + 1] + d[c + 1]) + fmaf(-4.f, m[c + 1], m[c] + m[c + 2]);
    dst[c] = v * rowm;
  }
  dst[0] *= wm0;
  dst[5] *= wm5;
}

// gradient + cumulative-binning for one output row (4 px) from lap rows A,B,C
// acc[0..8] = sums of mag where ang >= b_i (monotone boundaries), acc[9] = total
__device__ __forceinline__ void out_row4(const float A[6], const float B[6], const float C[6],
                                         float acc[10]) {
  float cs[6], dd[6];
#pragma unroll
  for (int c = 0; c < 6; ++c) {
    cs[c] = A[c] + fmaf(2.f, B[c], C[c]);
    dd[c] = C[c] - A[c];
  }
#pragma unroll
  for (int c = 0; c < 4; ++c) {
    float gx = cs[c + 2] - cs[c];
    float gy = fmaf(2.f, dd[c + 1], dd[c] + dd[c + 2]);
    float mag = __builtin_amdgcn_sqrtf(fmaf(gx, gx, fmaf(gy, gy, 1e-8f)));
    bool neg = gy < 0.f;
    float fx = neg ? -gx : gx;
    float fy = neg ? -gy : gy;
    float u, v;
    u = 0.17364817766693033f * fx; v = 0.984807753012208f * fy;
    acc[0] += (u <= v) ? mag : 0.f;
    acc[8] += (u <= -v) ? mag : 0.f;
    u = 0.5f * fx; v = 0.8660254037844387f * fy;
    acc[1] += (u <= v) ? mag : 0.f;
    acc[7] += (u <= -v) ? mag : 0.f;
    u = 0.766044443118978f * fx; v = 0.6427876096865393f * fy;
    acc[2] += (u <= v) ? mag : 0.f;
    acc[6] += (u <= -v) ? mag : 0.f;
    u = 0.9396926207859084f * fx; v = 0.3420201433256687f * fy;
    acc[3] += (u <= v) ? mag : 0.f;
    acc[5] += (u <= -v) ? mag : 0.f;
    acc[4] += (fx <= 0.f) ? mag : 0.f;
    acc[9] += mag;
  }
}

// one x row (8 floats, window cols gc0-2..gc0+5) from global, zero-filled OOB
__device__ __forceinline__ void load_grow(const float* __restrict__ xim, int gr, bool valid,
                                          int o0, int o1, int o2, int o3,
                                          float mlo, float mhi, float r[8]) {
  if (valid) {
    const float* p = xim + gr * W_IMG;
    float2 a = *reinterpret_cast<const float2*>(p + o0);
    float2 b = *reinterpret_cast<const float2*>(p + o1);
    float2 c = *reinterpret_cast<const float2*>(p + o2);
    float2 d = *reinterpret_cast<const float2*>(p + o3);
    r[0] = a.x * mlo; r[1] = a.y * mlo;
    r[2] = b.x;       r[3] = b.y;
    r[4] = c.x;       r[5] = c.y;
    r[6] = d.x * mhi; r[7] = d.y * mhi;
  } else {
#pragma unroll
    for (int i = 0; i < 8; ++i) r[i] = 0.f;
  }
}

__global__ __launch_bounds__(256) void phog_hist_kernel(const float* __restrict__ x,
                                                        float* __restrict__ hist2) {
  // XCD swizzle: give each XCD 64 whole bc-images (16 cells contiguous).
  const int f = blockIdx.y * 16 + blockIdx.x;   // 0..8191, HW xcd ~ f%8
  const int xcd = f & 7;
  const int idx = f >> 3;                       // 0..1023 within xcd
  const int bc = xcd * 64 + (idx >> 4);
  const int tile = idx & 15;                    // cell id (tr*4+tc)
  const int R0 = (tile >> 2) * 64;
  const int C0 = (tile & 3) * 64;
  const int tid = threadIdx.x;
  const int tcol = tid & 15;    // 4 cols each
  const int trow = tid >> 4;    // 4 rows each

  const float* xim = x + (size_t)bc * (H_IMG * W_IMG);

  const int gr0 = R0 + 4 * trow;  // first output row
  const int gc0 = C0 + 4 * tcol;  // first output col
  const int bcol = gc0 - 2;       // window col 0 (global)

  // clamped float2 offsets + masks for the 2 edge float2s
  const int o0 = (bcol < 0) ? 0 : bcol;
  const int o1 = gc0;
  const int o2 = gc0 + 2;
  const int o3 = (gc0 + 4 > 254) ? 254 : (gc0 + 4);
  const float mlo = (bcol >= 0) ? 1.f : 0.f;        // x cols gc0-2,gc0-1
  const float mhi = (gc0 + 5 <= 255) ? 1.f : 0.f;   // x cols gc0+4,gc0+5

  const bool vlo = gr0 > 0;     // x rows gr0-2, gr0-1 valid?
  const bool vhi = gr0 < 252;   // x rows gr0+4, gr0+5 valid?
  const float rm_first = vlo ? 1.f : 0.f;              // lap row gr0-1
  const float rm_last = (gr0 + 4 <= 255) ? 1.f : 0.f;  // lap row gr0+4
  const float wm0 = (gc0 >= 1) ? 1.f : 0.f;        // lap col gc0-1
  const float wm5 = (gc0 + 4 <= 255) ? 1.f : 0.f;  // lap col gc0+4

  // ---- load the ENTIRE 8-row window upfront: 32 independent loads, MLP=32
  float w0[8], w1[8], w2[8], w3[8], w4[8], w5[8], w6[8], w7[8];
  load_grow(xim, gr0 - 2, vlo, o0, o1, o2, o3, mlo, mhi, w0);
  load_grow(xim, gr0 - 1, vlo, o0, o1, o2, o3, mlo, mhi, w1);
  load_grow(xim, gr0 + 0, true, o0, o1, o2, o3, mlo, mhi, w2);
  load_grow(xim, gr0 + 1, true, o0, o1, o2, o3, mlo, mhi, w3);
  load_grow(xim, gr0 + 2, true, o0, o1, o2, o3, mlo, mhi, w4);
  load_grow(xim, gr0 + 3, true, o0, o1, o2, o3, mlo, mhi, w5);
  load_grow(xim, gr0 + 4, vhi, o0, o1, o2, o3, mlo, mhi, w6);
  load_grow(xim, gr0 + 5, vhi, o0, o1, o2, o3, mlo, mhi, w7);

  float acc[10];
#pragma unroll
  for (int k = 0; k < 10; ++k) acc[k] = 0.f;

  // ---- compute: 6 lap rows, 4 output rows (compiler overlaps with in-flight loads)
  float lA[6], lB[6], lC[6], lD[6];
  lap_row6(lA, w0, w1, w2, wm0, wm5, rm_first);  // lap gr0-1
  lap_row6(lB, w1, w2, w3, wm0, wm5, 1.f);       // lap gr0
  lap_row6(lC, w2, w3, w4, wm0, wm5, 1.f);       // lap gr0+1
  out_row4(lA, lB, lC, acc);                     // out gr0
  lap_row6(lD, w3, w4, w5, wm0, wm5, 1.f);       // lap gr0+2
  out_row4(lB, lC, lD, acc);                     // out gr0+1
  lap_row6(lA, w4, w5, w6, wm0, wm5, 1.f);       // lap gr0+3
  out_row4(lC, lD, lA, acc);                     // out gr0+2
  lap_row6(lB, w5, w6, w7, wm0, wm5, rm_last);   // lap gr0+4
  out_row4(lD, lA, lB, acc);                     // out gr0+3

  // ---- reduce: wave butterfly, then cross-wave via LDS
#pragma unroll
  for (int k = 0; k < 10; ++k) {
    float v = acc[k];
#pragma unroll
    for (int off = 32; off > 0; off >>= 1) v += __shfl_xor(v, off);
    acc[k] = v;
  }

  __shared__ float hred[4][10];
  __shared__ float hsum[10];
  const int lane = tid & 63;
  const int wave = tid >> 6;
  if (lane == 0) {
#pragma unroll
    for (int k = 0; k < 10; ++k) hred[wave][k] = acc[k];
  }
  __syncthreads();
  if (tid < 10) hsum[tid] = (hred[0][tid] + hred[1][tid]) + (hred[2][tid] + hred[3][tid]);
  __syncthreads();
  if (tid < 9) {
    float h = (tid == 0) ? ((hsum[9] - hsum[0]) + hsum[8]) : (hsum[tid - 1] - hsum[tid]);
    hist2[(bc * 16 + tile) * 9 + tid] = h;
  }
}

__global__ __launch_bounds__(256) void phog_norm_kernel(const float* __restrict__ hist2,
                                                        float* __restrict__ out) {
  int t = blockIdx.x * 256 + threadIdx.x;
  if (t >= 32 * 336) return;
  int b = t / 336;
  int r = t - b * 336;

  float h[9];
  if (r < 16) {
    const float* p = hist2 + (b * 16 + r) * 144;
#pragma unroll
    for (int k = 0; k < 9; ++k) {
      float s = 0.f;
#pragma unroll
      for (int cell = 0; cell < 16; ++cell) s += p[cell * 9 + k];
      h[k] = s;
    }
  } else if (r < 80) {
    int q = r - 16;
    int c = q >> 2;
    int cell = q & 3;
    int r1 = cell >> 1, c1 = cell & 1;
    const float* p = hist2 + (b * 16 + c) * 144;
    int i00 = ((2 * r1) * 4 + 2 * c1) * 9;
    int i01 = ((2 * r1) * 4 + 2 * c1 + 1) * 9;
    int i10 = ((2 * r1 + 1) * 4 + 2 * c1) * 9;
    int i11 = ((2 * r1 + 1) * 4 + 2 * c1 + 1) * 9;
#pragma unroll
    for (int k = 0; k < 9; ++k) h[k] = (p[i00 + k] + p[i01 + k]) + (p[i10 + k] + p[i11 + k]);
  } else {
    int q = r - 80;
    int c = q >> 4;
    int cell = q & 15;
    const float* p = hist2 + ((b * 16 + c) * 16 + cell) * 9;
#pragma unroll
    for (int k = 0; k < 9; ++k) h[k] = p[k];
  }

  float s = 0.f;
#pragma unroll
  for (int k = 0; k < 9; ++k) s += h[k];
  float inv = 1.f / (s + 1e-8f);
#pragma unroll
  for (int k = 0; k < 9; ++k) h[k] *= inv;
  float n2 = 0.f;
#pragma unroll
  for (int k = 0; k < 9; ++k) n2 = fmaf(h[k], h[k], n2);
  float nrm = sqrtf(n2);
  float inv2 = 1.f / fmaxf(nrm, 1e-12f);
#pragma unroll
  for (int k = 0; k < 9; ++k) out[t * 9 + k] = h[k] * inv2;
}

extern "C" void kernel_launch(void* const* d_in, const int* in_sizes, int n_in,
                              void* d_out, int out_size, void* d_ws, size_t ws_size,
                              hipStream_t stream) {
  const float* x = (const float*)d_in[0];
  float* out = (float*)d_out;
  float* hist2 = (float*)d_ws;  // 512*16*9 floats = 294912 B

  dim3 g1(16, 512);
  phog_hist_kernel<<<g1, 256, 0, stream>>>(x, hist2);

  int total = 32 * 336;
  phog_norm_kernel<<<(total + 255) / 256, 256, 0, stream>>>(hist2, out);
}

// Round 8
// 62.937 us; speedup vs baseline: 4.0898x; 1.0323x over previous
//
#include <hip/hip_runtime.h>

// PHOG: lap = dw3x3(x, laplacian); gx,gy = dw3x3(lap, sobel); mag/ang -> 9-bin
// hist over pyramid cells (1+4+16), L1-ish then L2 normalize.
//
// R8: VALU-minimized. Evidence: R2/R6/R7 all have dur*VALUBusy ~57us == timed
// duration -> issue-bound; cut instructions. (1) 8wx8t thread tiles (64 px):
// per-thread fixed costs /4, lap redundancy 1.5x->1.25x. (2) block = 8x32
// threads = 64x256 px -> each WAVE == one 64x64 cell: butterfly reduce only,
// no LDS, no barriers. (3) med3 binning: p = med3(fma(fy,C',-fx*S'),0,1)
// with 1e35-prescaled constants (saturates to exact 0/1; inf-safe), acc via
// fma -- 3 ops/boundary, no cmp/cndmask. (4) fx,fy via sign bit-ops.
// Rolling-3 x rows, loads 1 row ahead (VALU-bound, modest prefetch ok).

#define H_IMG 256
#define W_IMG 256

// boundary constants prescaled by 1e35: S'=sin(b)*1e35, C'=cos(b)*1e35
#define S0 1.7364817766693033e34f
#define C0 9.84807753012208e34f
#define S1 5.0e34f
#define C1 8.660254037844387e34f
#define S2 7.66044443118978e34f
#define C2 6.427876096865393e34f
#define S3 9.396926207859084e34f
#define C3 3.420201433256687e34f

// one x row: 12 floats = window cols gc0-2..gc0+9; OOB cols masked to 0
__device__ __forceinline__ void load_xrow12(const float* __restrict__ xim, int gr, bool valid,
                                            int o0, int o5, int gc0, float mlo, float mhi,
                                            float r[12]) {
  if (valid) {
    const float* p = xim + gr * W_IMG;
    float2 a = *reinterpret_cast<const float2*>(p + o0);
    float2 b = *reinterpret_cast<const float2*>(p + gc0);
    float2 c = *reinterpret_cast<const float2*>(p + gc0 + 2);
    float2 d = *reinterpret_cast<const float2*>(p + gc0 + 4);
    float2 e = *reinterpret_cast<const float2*>(p + gc0 + 6);
    float2 f = *reinterpret_cast<const float2*>(p + o5);
    r[0] = a.x * mlo; r[1] = a.y * mlo;
    r[2] = b.x;  r[3] = b.y;  r[4] = c.x;  r[5] = c.y;
    r[6] = d.x;  r[7] = d.y;  r[8] = e.x;  r[9] = e.y;
    r[10] = f.x * mhi; r[11] = f.y * mhi;
  } else {
#pragma unroll
    for (int i = 0; i < 12; ++i) r[i] = 0.f;
  }
}

// lap row (10 cols, lap col gc0-1+j) from x rows u,m,d (12-wide windows)
__device__ __forceinline__ void lap_row10(float dst[10], const float u[12], const float m[12],
                                          const float d[12], float wm0, float wm9, float rowm) {
#pragma unroll
  for (int j = 0; j < 10; ++j) {
    float v = (u[j + 1] + d[j + 1]) + fmaf(-4.f, m[j + 1], m[j] + m[j + 2]);
    dst[j] = v * rowm;
  }
  dst[0] *= wm0;
  dst[9] *= wm9;
}

// gradient + med3 cumulative binning for one output row (8 px) from lap rows A,B,C
// acc[0..8]: sums of mag where ang >= b_i; acc[9]: total mag
__device__ __forceinline__ void out_row8(const float A[10], const float B[10], const float C[10],
                                         float acc[10]) {
  float cs[10], dd[10];
#pragma unroll
  for (int j = 0; j < 10; ++j) {
    cs[j] = A[j] + fmaf(2.f, B[j], C[j]);
    dd[j] = C[j] - A[j];
  }
#pragma unroll
  for (int c = 0; c < 8; ++c) {
    float gx = cs[c + 2] - cs[c];
    float gy = fmaf(2.f, dd[c + 1], dd[c] + dd[c + 2]);
    float mag = __builtin_amdgcn_sqrtf(fmaf(gx, gx, fmaf(gy, gy, 1e-8f)));
    unsigned sg = __float_as_uint(gy) & 0x80000000u;
    float fx = __uint_as_float(__float_as_uint(gx) ^ sg);  // sign(gy)*gx
    float fy = fabsf(gy);
    // p_i = (ang>=b_i): t = C'*fy - S'*fx scaled 1e35 -> med3(t,0,1) is 0/1
    float b0 = fx * S0;
    acc[0] = fmaf(mag, __builtin_amdgcn_fmed3f(fmaf(fy, C0, -b0), 0.f, 1.f), acc[0]);
    acc[8] = fmaf(mag, __builtin_amdgcn_fmed3f(fmaf(fy, -C0, -b0), 0.f, 1.f), acc[8]);
    float b1 = fx * S1;
    acc[1] = fmaf(mag, __builtin_amdgcn_fmed3f(fmaf(fy, C1, -b1), 0.f, 1.f), acc[1]);
    acc[7] = fmaf(mag, __builtin_amdgcn_fmed3f(fmaf(fy, -C1, -b1), 0.f, 1.f), acc[7]);
    float b2 = fx * S2;
    acc[2] = fmaf(mag, __builtin_amdgcn_fmed3f(fmaf(fy, C2, -b2), 0.f, 1.f), acc[2]);
    acc[6] = fmaf(mag, __builtin_amdgcn_fmed3f(fmaf(fy, -C2, -b2), 0.f, 1.f), acc[6]);
    float b3 = fx * S3;
    acc[3] = fmaf(mag, __builtin_amdgcn_fmed3f(fmaf(fy, C3, -b3), 0.f, 1.f), acc[3]);
    acc[5] = fmaf(mag, __builtin_amdgcn_fmed3f(fmaf(fy, -C3, -b3), 0.f, 1.f), acc[5]);
    acc[4] = fmaf(mag, __builtin_amdgcn_fmed3f(fx * -1e35f, 0.f, 1.f), acc[4]);
    acc[9] += mag;
  }
}

__global__ __launch_bounds__(256) void phog_hist_kernel(const float* __restrict__ x,
                                                        float* __restrict__ hist2) {
  const int tc = blockIdx.x;   // cell col 0..3
  const int bc = blockIdx.y;   // 0..511
  const int tid = threadIdx.x;
  const int tcol = tid & 7;    // 8 threads x 8 px = 64 cols (one cell wide)
  const int trow = tid >> 3;   // 32 threads x 8 px = 256 rows (whole column)

  const float* xim = x + (size_t)bc * (H_IMG * W_IMG);

  const int gr0 = 8 * trow;            // first output row
  const int gc0 = tc * 64 + 8 * tcol;  // first output col

  // col handling: window cols gc0-2..gc0+9 as 6 float2; edge clamp + mask
  const int o0 = (gc0 - 2 < 0) ? 0 : (gc0 - 2);
  const int o5 = (gc0 + 8 > 254) ? 254 : (gc0 + 8);
  const float mlo = (gc0 - 2 >= 0) ? 1.f : 0.f;     // x cols gc0-2,gc0-1
  const float mhi = (gc0 + 9 <= 255) ? 1.f : 0.f;   // x cols gc0+8,gc0+9
  const float wm0 = (gc0 >= 1) ? 1.f : 0.f;         // lap col gc0-1
  const float wm9 = (gc0 + 8 <= 255) ? 1.f : 0.f;   // lap col gc0+8

  const bool vlo = trow > 0;    // x rows gr0-2,gr0-1
  const bool vhi = trow < 31;   // x rows gr0+8,gr0+9
  const float rmf = vlo ? 1.f : 0.f;  // lap row gr0-1
  const float rml = vhi ? 1.f : 0.f;  // lap row gr0+8

  float acc[10];
#pragma unroll
  for (int k = 0; k < 10; ++k) acc[k] = 0.f;

  float xa[12], xb[12], xc[12];      // rolling x rows
  float La[10], Lb[10], Lc[10];      // rolling lap rows

  // x rows i=0..11 at global row gr0-2+i; lap rows j=0..9 at gr0-1+j
  load_xrow12(xim, gr0 - 2, vlo, o0, o5, gc0, mlo, mhi, xa);
  load_xrow12(xim, gr0 - 1, vlo, o0, o5, gc0, mlo, mhi, xb);
  load_xrow12(xim, gr0 + 0, true, o0, o5, gc0, mlo, mhi, xc);
  lap_row10(La, xa, xb, xc, wm0, wm9, rmf);      // lap 0
  load_xrow12(xim, gr0 + 1, true, o0, o5, gc0, mlo, mhi, xa);
  lap_row10(Lb, xb, xc, xa, wm0, wm9, 1.f);      // lap 1
  load_xrow12(xim, gr0 + 2, true, o0, o5, gc0, mlo, mhi, xb);
  lap_row10(Lc, xc, xa, xb, wm0, wm9, 1.f);      // lap 2
  out_row8(La, Lb, Lc, acc);                     // out 0
  load_xrow12(xim, gr0 + 3, true, o0, o5, gc0, mlo, mhi, xc);
  lap_row10(La, xa, xb, xc, wm0, wm9, 1.f);      // lap 3
  out_row8(Lb, Lc, La, acc);                     // out 1
  load_xrow12(xim, gr0 + 4, true, o0, o5, gc0, mlo, mhi, xa);
  lap_row10(Lb, xb, xc, xa, wm0, wm9, 1.f);      // lap 4
  out_row8(Lc, La, Lb, acc);                     // out 2
  load_xrow12(xim, gr0 + 5, true, o0, o5, gc0, mlo, mhi, xb);
  lap_row10(Lc, xc, xa, xb, wm0, wm9, 1.f);      // lap 5
  out_row8(La, Lb, Lc, acc);                     // out 3
  load_xrow12(xim, gr0 + 6, true, o0, o5, gc0, mlo, mhi, xc);
  lap_row10(La, xa, xb, xc, wm0, wm9, 1.f);      // lap 6
  out_row8(Lb, Lc, La, acc);                     // out 4
  load_xrow12(xim, gr0 + 7, true, o0, o5, gc0, mlo, mhi, xa);
  lap_row10(Lb, xb, xc, xa, wm0, wm9, 1.f);      // lap 7
  out_row8(Lc, La, Lb, acc);                     // out 5
  load_xrow12(xim, gr0 + 8, vhi, o0, o5, gc0, mlo, mhi, xb);
  lap_row10(Lc, xc, xa, xb, wm0, wm9, 1.f);      // lap 8
  out_row8(La, Lb, Lc, acc);                     // out 6
  load_xrow12(xim, gr0 + 9, vhi, o0, o5, gc0, mlo, mhi, xc);
  lap_row10(La, xa, xb, xc, wm0, wm9, rml);      // lap 9
  out_row8(Lb, Lc, La, acc);                     // out 7

  // wave = exactly one 64x64 cell -> full 64-lane butterfly, no LDS/barriers
#pragma unroll
  for (int k = 0; k < 10; ++k) {
    float v = acc[k];
#pragma unroll
    for (int off = 32; off > 0; off >>= 1) v += __shfl_xor(v, off);
    acc[k] = v;
  }
  const int lane = tid & 63;
  const int w = tid >> 6;  // wave id == cell row
  if (lane == 0) {
    float* dst = &hist2[((bc * 16) + (w * 4 + tc)) * 9];
    dst[0] = (acc[9] - acc[0]) + acc[8];
#pragma unroll
    for (int k = 1; k < 9; ++k) dst[k] = acc[k - 1] - acc[k];
  }
}

__global__ __launch_bounds__(256) void phog_norm_kernel(const float* __restrict__ hist2,
                                                        float* __restrict__ out) {
  int t = blockIdx.x * 256 + threadIdx.x;
  if (t >= 32 * 336) return;
  int b = t / 336;
  int r = t - b * 336;

  float h[9];
  if (r < 16) {
    const float* p = hist2 + (b * 16 + r) * 144;
#pragma unroll
    for (int k = 0; k < 9; ++k) {
      float s = 0.f;
#pragma unroll
      for (int cell = 0; cell < 16; ++cell) s += p[cell * 9 + k];
      h[k] = s;
    }
  } else if (r < 80) {
    int q = r - 16;
    int c = q >> 2;
    int cell = q & 3;
    int r1 = cell >> 1, c1 = cell & 1;
    const float* p = hist2 + (b * 16 + c) * 144;
    int i00 = ((2 * r1) * 4 + 2 * c1) * 9;
    int i01 = ((2 * r1) * 4 + 2 * c1 + 1) * 9;
    int i10 = ((2 * r1 + 1) * 4 + 2 * c1) * 9;
    int i11 = ((2 * r1 + 1) * 4 + 2 * c1 + 1) * 9;
#pragma unroll
    for (int k = 0; k < 9; ++k) h[k] = (p[i00 + k] + p[i01 + k]) + (p[i10 + k] + p[i11 + k]);
  } else {
    int q = r - 80;
    int c = q >> 4;
    int cell = q & 15;
    const float* p = hist2 + ((b * 16 + c) * 16 + cell) * 9;
#pragma unroll
    for (int k = 0; k < 9; ++k) h[k] = p[k];
  }

  float s = 0.f;
#pragma unroll
  for (int k = 0; k < 9; ++k) s += h[k];
  float inv = 1.f / (s + 1e-8f);
#pragma unroll
  for (int k = 0; k < 9; ++k) h[k] *= inv;
  float n2 = 0.f;
#pragma unroll
  for (int k = 0; k < 9; ++k) n2 = fmaf(h[k], h[k], n2);
  float nrm = sqrtf(n2);
  float inv2 = 1.f / fmaxf(nrm, 1e-12f);
#pragma unroll
  for (int k = 0; k < 9; ++k) out[t * 9 + k] = h[k] * inv2;
}

extern "C" void kernel_launch(void* const* d_in, const int* in_sizes, int n_in,
                              void* d_out, int out_size, void* d_ws, size_t ws_size,
                              hipStream_t stream) {
  const float* x = (const float*)d_in[0];
  float* out = (float*)d_out;
  float* hist2 = (float*)d_ws;  // 512*16*9 floats = 294912 B

  dim3 g1(4, 512);
  phog_hist_kernel<<<g1, 256, 0, stream>>>(x, hist2);

  int total = 32 * 336;
  phog_norm_kernel<<<(total + 255) / 256, 256, 0, stream>>>(hist2, out);
}